// Round 9
// baseline (435.094 us; speedup 1.0000x reference)
//
#include <hip/hip_runtime.h>
#include <math.h>

#define BB 2
#define TT 8192
#define HH 8
#define DD 64
#define NCC 128
#define MM 4
#define WW (TT/NCC)     // 64
#define T2 (2*TT)
#define CH 64           // clusters per kdist block (c-split x2)
#define SMAX 32         // slot cap per target row (cnt<=NC=128; overflow path below)
#define SK 68           // LDS row stride: 68*4=272 B, 16B-aligned -> ds_read_b128
#define TIEMAX 256

// ---------------- Kernel A: normalize + cdist + per-t' min via atomicMin ----------------
// Math body ROUND-3 VERBATIM (frozen contraction order). Round-7/8 diagnosis:
// compiler REMATERIALIZES x[64] per cluster (VGPR_Count=40); pinning x via
// empty asm forced liveness but (256,4)'s 16-wave floor pushed the allocator
// to the <=64-VGPR tier -> 64 regs + SCRATCH SPILL (WRITE +8MB, 127us).
// This round: keep the pin, relax to __launch_bounds__(256,2) (VGPR cap 256).
// ~105 VGPR is still the <=128 tier = 16 waves/CU = the occupancy we already
// measure, so nothing is lost and both remat and spill disappear.
// Bit-identical arithmetic (same values, same d=0..63 chain).
__global__ __launch_bounds__(256, 2) void kdist(
    const float* __restrict__ q, const float* __restrict__ k,
    const float* __restrict__ means,
    float* __restrict__ qd, float* __restrict__ kd,
    unsigned int* __restrict__ minb)
{
  __shared__ float sm2[CH];
  const int b = blockIdx.z >> 1, h = blockIdx.y;
  const int c0 = (blockIdx.z & 1) * CH;
  const int tid = threadIdx.x;

  if (tid < CH) {
    const float* mrow = means + ((size_t)h * NCC + c0 + tid) * DD;
    float s = 0.f;
    #pragma unroll
    for (int d = 0; d < DD; ++d) { float v = mrow[d]; s += v * v; }
    sm2[tid] = s;
  }
  __syncthreads();

  const int tp = blockIdx.x * 256 + tid;               // t' in [0,2T)
  const size_t bh = (size_t)(b * HH + h);
  const float* src = (tp < TT) ? (q + (bh * TT + tp) * DD)
                               : (k + (bh * TT + (tp - TT)) * DD);
  float x[DD];
  float ss = 0.f;
  #pragma unroll
  for (int i = 0; i < DD / 4; ++i) {
    float4 v = ((const float4*)src)[i];
    x[4*i] = v.x; x[4*i+1] = v.y; x[4*i+2] = v.z; x[4*i+3] = v.w;
    ss += v.x*v.x + v.y*v.y + v.z*v.z + v.w*v.w;
  }
  const float scale = 1.f / (sqrtf(ss) + 1e-6f);
  float x2 = 0.f;
  #pragma unroll
  for (int i = 0; i < DD; ++i) { x[i] *= scale; x2 += x[i] * x[i]; }

  // Pin x[] in VGPRs: opaque defs -> no rematerialization (no code emitted).
  #pragma unroll
  for (int i = 0; i < DD; i += 4)
    asm volatile("" : "+v"(x[i]), "+v"(x[i+1]), "+v"(x[i+2]), "+v"(x[i+3]));

  float* dst = (tp < TT) ? (qd + (bh * NCC) * TT + tp)
                         : (kd + (bh * NCC) * TT + (tp - TT));
  float mind2 = 1e30f;
  const float* mbase = means + ((size_t)h * NCC + c0) * DD;
  for (int c = 0; c < CH; ++c) {
    const float* mrow = mbase + (size_t)c * DD;        // wave-uniform -> s_load
    float dot = 0.f;
    #pragma unroll
    for (int d = 0; d < DD; ++d) dot += x[d] * mrow[d];
    float d2 = fmaxf(x2 + sm2[c] - 2.f * dot, 0.f);
    mind2 = fminf(mind2, d2);
    dst[(size_t)(c0 + c) * TT] = sqrtf(d2);
  }

  atomicMin(&minb[bh * T2 + tp], __float_as_uint(mind2));   // d2>=0: bits monotone
}

// ---------------- Kernel A2: sum per-t' minima -> aux ----------------
__global__ __launch_bounds__(256) void kaux(
    const unsigned int* __restrict__ minb, float* __restrict__ aux)
{
  __shared__ float red[4];
  const int i = blockIdx.x * 256 + threadIdx.x;        // over BB*HH*T2
  float v = __uint_as_float(minb[i]);
  #pragma unroll
  for (int off = 32; off; off >>= 1) v += __shfl_down(v, off, 64);
  if ((threadIdx.x & 63) == 0) red[threadIdx.x >> 6] = v;
  __syncthreads();
  if (threadIdx.x == 0) atomicAdd(aux, red[0] + red[1] + red[2] + red[3]);
}

// ---------------- Kernel B: top-64 smallest per row, register-resident ----------------
// Round-6 form (validated): 1-bit rounds, count via __popcll(__ballot(pred))
// (v_cmp on VALU + s_bcnt1/s_add on the concurrent scalar pipe), per-round
// redA slots -> one barrier per round. Counts integer-identical to the
// original shuffle-reduce version -> tau/ties/selection bit-identical.
__global__ __launch_bounds__(256) void ktopk(
    const float* __restrict__ qd, const float* __restrict__ kd,
    int* __restrict__ idxq, int* __restrict__ idxk)
{
  __shared__ unsigned int redA[32][4];
  __shared__ int outIdx[WW];
  __shared__ int tie[TIEMAX];
  __shared__ int pos, tpos;

  const int c = blockIdx.x, h = blockIdx.y;
  const int b = blockIdx.z >> 1, isK = blockIdx.z & 1;
  const int tid = threadIdx.x;
  const int lane = tid & 63, wid = tid >> 6;
  const size_t rowoff = ((size_t)(b * HH + h) * NCC + c) * TT;
  const float4* row4 = (const float4*)((isK ? kd : qd) + rowoff);

  unsigned int u[32];
  #pragma unroll
  for (int j = 0; j < 8; ++j) {
    float4 v = row4[j * 256 + tid];          // u[4j+m] is at index j*1024+tid*4+m
    u[4*j+0] = __float_as_uint(v.x);
    u[4*j+1] = __float_as_uint(v.y);
    u[4*j+2] = __float_as_uint(v.z);
    u[4*j+3] = __float_as_uint(v.w);
  }
  if (tid == 0) { pos = 0; tpos = 0; }

  unsigned int tau = 0u;
  for (int bit = 30; bit >= 0; --bit) {      // bit31 = sign, always 0 for dist
    const unsigned int cand = tau | (1u << bit);
    unsigned int cnt = 0;
    #pragma unroll
    for (int i = 0; i < 32; ++i)
      cnt += (unsigned int)__popcll(__ballot(u[i] < cand));   // SALU count
    if (lane == 0) redA[bit][wid] = cnt;     // wave-uniform value
    __syncthreads();                         // slot [bit] never rewritten -> 1 barrier
    const int tot = (int)(redA[bit][0] + redA[bit][1] + redA[bit][2] + redA[bit][3]);
    if (tot < WW) tau = cand;                // 64th smallest >= cand
  }
  {
    unsigned int cnt = 0;
    #pragma unroll
    for (int i = 0; i < 32; ++i)
      cnt += (unsigned int)__popcll(__ballot(u[i] < tau));
    if (lane == 0) redA[31][wid] = cnt;
  }
  __syncthreads();
  const int base = (int)(redA[31][0] + redA[31][1] + redA[31][2] + redA[31][3]);
  const int need = WW - base;

  #pragma unroll
  for (int i = 0; i < 32; ++i) {
    const int idx = (i >> 2) * 1024 + tid * 4 + (i & 3);
    if (u[i] < tau) {
      int p = atomicAdd(&pos, 1); outIdx[p] = idx;
    } else if (u[i] == tau) {
      int p = atomicAdd(&tpos, 1);
      if (p < TIEMAX) tie[p] = idx;          // >TIEMAX exact-equal values: pathological
    }
  }
  __syncthreads();
  const int tc = tpos < TIEMAX ? tpos : TIEMAX;
  if (tc == need) {
    if (tid < need) outIdx[base + tid] = tie[tid];   // all ties taken; order irrelevant
  } else if (tid == 0) {
    int last = -1;                            // rare: pick `need` lowest tie indices
    for (int e = 0; e < need; ++e) {
      int mn = 0x7fffffff;
      for (int s = 0; s < tc; ++s) { int t = tie[s]; if (t > last && t < mn) mn = t; }
      outIdx[base + e] = mn; last = mn;
    }
  }
  __syncthreads();
  int* dstp = (isK ? idxk : idxq) + ((size_t)(b * HH + h) * NCC + c) * WW;
  if (tid < WW) dstp[tid] = outIdx[tid];
}

// ---------------- Kernel C: gather + attention -> dense per-cluster out ----------------
// grid: (NC, H, B), block 256. SK=68 -> b128 LDS reads. P round-trips through
// LDS (reusing Ks after QK^T), so PV accumulators are CONSTANT-indexed float4
// (round-7 lesson: any per-lane-variable index into a register array demotes
// it to scratch -> GBs of spill traffic). No atomics; coalesced stores.
__global__ __launch_bounds__(256) void kattn(
    const float* __restrict__ q, const float* __restrict__ kg,
    const float* __restrict__ vg, const float* __restrict__ memk,
    const float* __restrict__ memv, const int* __restrict__ idxq,
    const int* __restrict__ idxk, float* __restrict__ outc)
{
  __shared__ float Ks[(MM + WW) * SK];   // 68 x 68 floats = 18.5 KB; becomes Ps
  __shared__ float Vs[(MM + WW) * SK];
  __shared__ int tq[WW];
  __shared__ int tk[WW];

  const int c = blockIdx.x, h = blockIdx.y, b = blockIdx.z;
  const int tid = threadIdx.x;
  const size_t bh = (size_t)(b * HH + h);

  if (tid < WW) tq[tid] = idxq[(bh * NCC + c) * WW + tid];
  else if (tid < 2 * WW) tk[tid - WW] = idxk[(bh * NCC + c) * WW + tid - WW];
  __syncthreads();

  const int r = tid >> 2, part = tid & 3;

  for (int j = r; j < MM + WW; j += 64) {
    const float* sk = (j < MM)
        ? memk + (((size_t)(h * NCC + c)) * MM + j) * DD + part * 16
        : kg + (bh * TT + tk[j - MM]) * DD + part * 16;
    const float* sv = (j < MM)
        ? memv + (((size_t)(h * NCC + c)) * MM + j) * DD + part * 16
        : vg + (bh * TT + tk[j - MM]) * DD + part * 16;
    #pragma unroll
    for (int i = 0; i < 4; ++i) {
      *(float4*)&Ks[j * SK + part * 16 + 4 * i] = ((const float4*)sk)[i];
      *(float4*)&Vs[j * SK + part * 16 + 4 * i] = ((const float4*)sv)[i];
    }
  }
  __syncthreads();

  // QK^T: thread (r, part) handles keys j = part*17 + jj
  float s[17];
  {
    float qr[DD];
    const float* qsrc = q + (bh * TT + tq[r]) * DD;
    #pragma unroll
    for (int i = 0; i < DD / 4; ++i) {
      float4 v = ((const float4*)qsrc)[i];
      qr[4*i] = v.x; qr[4*i+1] = v.y; qr[4*i+2] = v.z; qr[4*i+3] = v.w;
    }
    #pragma unroll
    for (int jj = 0; jj < 17; ++jj) {
      const float4* krow = (const float4*)&Ks[(part * 17 + jj) * SK];
      float a0 = 0.f, a1 = 0.f, a2 = 0.f, a3 = 0.f;
      #pragma unroll
      for (int i = 0; i < DD / 4; ++i) {
        float4 kv = krow[i];
        a0 = fmaf(qr[4*i+0], kv.x, a0);
        a1 = fmaf(qr[4*i+1], kv.y, a1);
        a2 = fmaf(qr[4*i+2], kv.z, a2);
        a3 = fmaf(qr[4*i+3], kv.w, a3);
      }
      s[jj] = ((a0 + a1) + (a2 + a3)) * 0.125f;
    }
  }
  // softmax across the quad (4 lanes = one query row)
  float mx = s[0];
  #pragma unroll
  for (int jj = 1; jj < 17; ++jj) mx = fmaxf(mx, s[jj]);
  mx = fmaxf(mx, __shfl_xor(mx, 1, 64));
  mx = fmaxf(mx, __shfl_xor(mx, 2, 64));
  float sum = 0.f;
  #pragma unroll
  for (int jj = 0; jj < 17; ++jj) { s[jj] = expf(s[jj] - mx); sum += s[jj]; }
  sum += __shfl_xor(sum, 1, 64);
  sum += __shfl_xor(sum, 2, 64);
  const float inv = 1.f / sum;
  #pragma unroll
  for (int jj = 0; jj < 17; ++jj) s[jj] *= inv;

  __syncthreads();                       // all QK reads of Ks complete
  #pragma unroll
  for (int jj = 0; jj < 17; ++jj) Ks[r * SK + part * 17 + jj] = s[jj];
  __syncthreads();                       // Ps ready

  // PV: thread (r, part) owns out[r][part*16 .. part*16+16) — constant-index accs
  float4 a0 = make_float4(0.f,0.f,0.f,0.f), a1 = a0, a2 = a0, a3 = a0;
  for (int j = 0; j < MM + WW; ++j) {
    const float p = Ks[r * SK + j];
    const float4* vrow = (const float4*)&Vs[j * SK + part * 16];
    float4 v0 = vrow[0], v1 = vrow[1], v2 = vrow[2], v3 = vrow[3];
    a0.x = fmaf(p, v0.x, a0.x); a0.y = fmaf(p, v0.y, a0.y);
    a0.z = fmaf(p, v0.z, a0.z); a0.w = fmaf(p, v0.w, a0.w);
    a1.x = fmaf(p, v1.x, a1.x); a1.y = fmaf(p, v1.y, a1.y);
    a1.z = fmaf(p, v1.z, a1.z); a1.w = fmaf(p, v1.w, a1.w);
    a2.x = fmaf(p, v2.x, a2.x); a2.y = fmaf(p, v2.y, a2.y);
    a2.z = fmaf(p, v2.z, a2.z); a2.w = fmaf(p, v2.w, a2.w);
    a3.x = fmaf(p, v3.x, a3.x); a3.y = fmaf(p, v3.y, a3.y);
    a3.z = fmaf(p, v3.z, a3.z); a3.w = fmaf(p, v3.w, a3.w);
  }
  float4* obase = (float4*)(outc + (((bh * NCC + c) * WW) + r) * DD + part * 16);
  obase[0] = a0; obase[1] = a1; obase[2] = a2; obase[3] = a3;
}

// ---------------- Kernel C2: inverted index (one int atomic per selection) ----------------
__global__ __launch_bounds__(256) void kindex(
    const int* __restrict__ idxq, const float* __restrict__ outc,
    int* __restrict__ cnt, int* __restrict__ slots, float* __restrict__ out)
{
  const int i = blockIdx.x * 256 + threadIdx.x;       // over B*H*NC*W
  const int bh = i >> 13;                             // NC*W = 8192
  const int e = i & 8191;
  const int t = idxq[i];
  const int row = bh * TT + t;
  const int p = atomicAdd(&cnt[row], 1);
  if (p < SMAX) {
    slots[(size_t)row * SMAX + p] = e;
  } else {
    const float* src = outc + ((size_t)(bh * (NCC * WW)) + e) * DD;
    for (int d = 0; d < DD; ++d) atomicAdd(&out[(size_t)row * DD + d], src[d]);
  }
}

// ---------------- Kernel D: gather slots + divide + aux ----------------
__global__ __launch_bounds__(256) void kfinal(
    float* __restrict__ outp, const int* __restrict__ cnt,
    const int* __restrict__ slots, const float* __restrict__ outc,
    const float* __restrict__ aux)
{
  const size_t n = (size_t)BB * HH * TT * DD;
  const size_t i = (size_t)blockIdx.x * 256 + threadIdx.x;
  if (i < n) {
    const int row = (int)(i >> 6);
    const int d = (int)(i & 63);
    const int bh = row >> 13;
    const int c = cnt[row];
    const int m = c < SMAX ? c : SMAX;
    float sum = outp[i];
    for (int s = 0; s < m; ++s) {
      const int e = slots[(size_t)row * SMAX + s];
      sum += outc[((size_t)(bh * (NCC * WW)) + e) * DD + d];
    }
    outp[i] = sum / ((float)c + 1e-5f);
  }
  if (i == 0) outp[n] = aux[0] * (0.0001f / (float)((size_t)BB * HH * 2 * TT * DD));
}

extern "C" void kernel_launch(void* const* d_in, const int* in_sizes, int n_in,
                              void* d_out, int out_size, void* d_ws, size_t ws_size,
                              hipStream_t stream) {
  (void)in_sizes; (void)n_in; (void)out_size; (void)ws_size;
  const float* q     = (const float*)d_in[0];
  const float* k     = (const float*)d_in[1];
  const float* v     = (const float*)d_in[2];
  const float* means = (const float*)d_in[3];
  const float* memk  = (const float*)d_in[4];
  const float* memv  = (const float*)d_in[5];
  float* out = (float*)d_out;

  const size_t NQ   = (size_t)BB * HH * NCC * TT;   // 16,777,216
  const size_t NIDX = (size_t)BB * HH * NCC * WW;   // 131,072
  const size_t NROW = (size_t)BB * HH * TT;         // 131,072
  const size_t NMIN = (size_t)BB * HH * T2;         // 262,144

  float*        qd   = (float*)d_ws;
  float*        kd   = qd + NQ;
  int*          idxq = (int*)(kd + NQ);
  int*          idxk = idxq + NIDX;
  int*          cnt  = idxk + NIDX;
  float*        aux  = (float*)(cnt + NROW);
  unsigned int* minb = (unsigned int*)(aux + 1);
  float*        outc  = qd;                         // dead after ktopk -> reuse
  int*          slots = (int*)kd;

  const size_t n = (size_t)BB * HH * TT * DD;
  hipMemsetAsync(out, 0, n * sizeof(float), stream);
  hipMemsetAsync(cnt, 0, (NROW + 1) * sizeof(int), stream);   // cnt + aux
  hipMemsetAsync(minb, 0x7f, NMIN * sizeof(unsigned int), stream);  // +inf-ish floats

  kdist<<<dim3(T2 / 256, HH, BB * 2), 256, 0, stream>>>(q, k, means, qd, kd, minb);
  kaux<<<(int)(NMIN / 256), 256, 0, stream>>>(minb, aux);
  ktopk<<<dim3(NCC, HH, 2 * BB), 256, 0, stream>>>(qd, kd, idxq, idxk);
  kattn<<<dim3(NCC, HH, BB), 256, 0, stream>>>(q, k, v, memk, memv, idxq, idxk, outc);
  kindex<<<(int)(NIDX / 256), 256, 0, stream>>>(idxq, outc, cnt, slots, out);
  kfinal<<<(int)((n + 255) / 256), 256, 0, stream>>>(out, cnt, slots, outc, aux);
}

// Round 10
// 417.198 us; speedup vs baseline: 1.0429x; 1.0429x over previous
//
#include <hip/hip_runtime.h>
#include <math.h>

#define BB 2
#define TT 8192
#define HH 8
#define DD 64
#define NCC 128
#define MM 4
#define WW (TT/NCC)     // 64
#define T2 (2*TT)
#define CH 64           // clusters per kdist block (c-split x2)
#define SMAX 32         // slot cap per target row (cnt<=NC=128; overflow path below)
#define SK 68           // LDS row stride: 68*4=272 B, 16B-aligned -> ds_read_b128
#define TIEMAX 256

// ---------------- Kernel A: normalize + cdist + per-t' min via atomicMin ----------------
// ROUND-3 VERBATIM — PERMANENTLY FROZEN. Means rows wave-uniform -> scalar
// s_load + v_fma(v,s,v); 116us, VALU 74%, occ 50%. Post-mortem of rounds
// 1/4/7/8/9: VALU-busy TIME is ~86us in every variant; ILP/pin/launch_bounds
// changes only shifted occupancy and exposed MORE stall (130/127/135us).
// The no-hint allocator's 40-VGPR choice maximizes resident waves = best
// stall hiding. Do not touch: no ILP, no pins, no launch_bounds hints.
__global__ __launch_bounds__(256) void kdist(
    const float* __restrict__ q, const float* __restrict__ k,
    const float* __restrict__ means,
    float* __restrict__ qd, float* __restrict__ kd,
    unsigned int* __restrict__ minb)
{
  __shared__ float sm2[CH];
  const int b = blockIdx.z >> 1, h = blockIdx.y;
  const int c0 = (blockIdx.z & 1) * CH;
  const int tid = threadIdx.x;

  if (tid < CH) {
    const float* mrow = means + ((size_t)h * NCC + c0 + tid) * DD;
    float s = 0.f;
    #pragma unroll
    for (int d = 0; d < DD; ++d) { float v = mrow[d]; s += v * v; }
    sm2[tid] = s;
  }
  __syncthreads();

  const int tp = blockIdx.x * 256 + tid;               // t' in [0,2T)
  const size_t bh = (size_t)(b * HH + h);
  const float* src = (tp < TT) ? (q + (bh * TT + tp) * DD)
                               : (k + (bh * TT + (tp - TT)) * DD);
  float x[DD];
  float ss = 0.f;
  #pragma unroll
  for (int i = 0; i < DD / 4; ++i) {
    float4 v = ((const float4*)src)[i];
    x[4*i] = v.x; x[4*i+1] = v.y; x[4*i+2] = v.z; x[4*i+3] = v.w;
    ss += v.x*v.x + v.y*v.y + v.z*v.z + v.w*v.w;
  }
  const float scale = 1.f / (sqrtf(ss) + 1e-6f);
  float x2 = 0.f;
  #pragma unroll
  for (int i = 0; i < DD; ++i) { x[i] *= scale; x2 += x[i] * x[i]; }

  float* dst = (tp < TT) ? (qd + (bh * NCC) * TT + tp)
                         : (kd + (bh * NCC) * TT + (tp - TT));
  float mind2 = 1e30f;
  const float* mbase = means + ((size_t)h * NCC + c0) * DD;
  for (int c = 0; c < CH; ++c) {
    const float* mrow = mbase + (size_t)c * DD;        // wave-uniform -> s_load
    float dot = 0.f;
    #pragma unroll
    for (int d = 0; d < DD; ++d) dot += x[d] * mrow[d];
    float d2 = fmaxf(x2 + sm2[c] - 2.f * dot, 0.f);
    mind2 = fminf(mind2, d2);
    dst[(size_t)(c0 + c) * TT] = sqrtf(d2);
  }

  atomicMin(&minb[bh * T2 + tp], __float_as_uint(mind2));   // d2>=0: bits monotone
}

// ---------------- Kernel A2: sum per-t' minima -> aux ----------------
__global__ __launch_bounds__(256) void kaux(
    const unsigned int* __restrict__ minb, float* __restrict__ aux)
{
  __shared__ float red[4];
  const int i = blockIdx.x * 256 + threadIdx.x;        // over BB*HH*T2
  float v = __uint_as_float(minb[i]);
  #pragma unroll
  for (int off = 32; off; off >>= 1) v += __shfl_down(v, off, 64);
  if ((threadIdx.x & 63) == 0) red[threadIdx.x >> 6] = v;
  __syncthreads();
  if (threadIdx.x == 0) atomicAdd(aux, red[0] + red[1] + red[2] + red[3]);
}

// ---------------- Kernel B: top-64 smallest per row, register-resident ----------------
// Shuffle-reduce form (the 412.9us-measured config). Ballot/SALU variant
// (rounds 6/7) measured ~+6us total twice -> reverted. Row in registers
// (u[32]/thread); bitwise binary search for tau; lowest-index ties match
// jax.lax.top_k.
__global__ __launch_bounds__(256) void ktopk(
    const float* __restrict__ qd, const float* __restrict__ kd,
    int* __restrict__ idxq, int* __restrict__ idxk)
{
  __shared__ unsigned int red[4];
  __shared__ int outIdx[WW];
  __shared__ int tie[TIEMAX];
  __shared__ int pos, tpos;

  const int c = blockIdx.x, h = blockIdx.y;
  const int b = blockIdx.z >> 1, isK = blockIdx.z & 1;
  const int tid = threadIdx.x;
  const int lane = tid & 63, wid = tid >> 6;
  const size_t rowoff = ((size_t)(b * HH + h) * NCC + c) * TT;
  const float4* row4 = (const float4*)((isK ? kd : qd) + rowoff);

  unsigned int u[32];
  #pragma unroll
  for (int j = 0; j < 8; ++j) {
    float4 v = row4[j * 256 + tid];          // u[4j+m] is at index j*1024+tid*4+m
    u[4*j+0] = __float_as_uint(v.x);
    u[4*j+1] = __float_as_uint(v.y);
    u[4*j+2] = __float_as_uint(v.z);
    u[4*j+3] = __float_as_uint(v.w);
  }
  if (tid == 0) { pos = 0; tpos = 0; }

  unsigned int tau = 0u;
  for (int bit = 30; bit >= 0; --bit) {      // bit31 = sign, always 0 for dist
    const unsigned int cand = tau | (1u << bit);
    int cnt = 0;
    #pragma unroll
    for (int i = 0; i < 32; ++i) cnt += (u[i] < cand) ? 1 : 0;
    #pragma unroll
    for (int off = 32; off; off >>= 1) cnt += __shfl_down(cnt, off, 64);
    if (lane == 0) red[wid] = (unsigned int)cnt;
    __syncthreads();
    const int tot = (int)(red[0] + red[1] + red[2] + red[3]);
    if (tot < WW) tau = cand;                // 64th smallest >= cand
    __syncthreads();
  }
  {
    int cnt = 0;
    #pragma unroll
    for (int i = 0; i < 32; ++i) cnt += (u[i] < tau) ? 1 : 0;
    #pragma unroll
    for (int off = 32; off; off >>= 1) cnt += __shfl_down(cnt, off, 64);
    if (lane == 0) red[wid] = (unsigned int)cnt;
  }
  __syncthreads();
  const int base = (int)(red[0] + red[1] + red[2] + red[3]);
  const int need = WW - base;

  #pragma unroll
  for (int i = 0; i < 32; ++i) {
    const int idx = (i >> 2) * 1024 + tid * 4 + (i & 3);
    if (u[i] < tau) {
      int p = atomicAdd(&pos, 1); outIdx[p] = idx;
    } else if (u[i] == tau) {
      int p = atomicAdd(&tpos, 1);
      if (p < TIEMAX) tie[p] = idx;          // >TIEMAX exact-equal values: pathological
    }
  }
  __syncthreads();
  const int tc = tpos < TIEMAX ? tpos : TIEMAX;
  if (tc == need) {
    if (tid < need) outIdx[base + tid] = tie[tid];   // all ties taken; order irrelevant
  } else if (tid == 0) {
    int last = -1;                            // rare: pick `need` lowest tie indices
    for (int e = 0; e < need; ++e) {
      int mn = 0x7fffffff;
      for (int s = 0; s < tc; ++s) { int t = tie[s]; if (t > last && t < mn) mn = t; }
      outIdx[base + e] = mn; last = mn;
    }
  }
  __syncthreads();
  int* dstp = (isK ? idxk : idxq) + ((size_t)(b * HH + h) * NCC + c) * WW;
  if (tid < WW) dstp[tid] = outIdx[tid];
}

// ---------------- Kernel C: gather + attention -> dense per-cluster out ----------------
// grid: (NC, H, B), block 256. SK=68 -> b128 LDS reads. P round-trips through
// LDS (reusing Ks after QK^T), so PV accumulators are CONSTANT-indexed float4.
// NEW (round 10): q-row load hoisted ABOVE the K/V staging loop (T14
// issue-early/consume-late) — its HBM/L2 latency now hides under ~33 staging
// iterations instead of being exposed right before QK^T. Same values, same
// contraction order -> numerics unchanged.
__global__ __launch_bounds__(256) void kattn(
    const float* __restrict__ q, const float* __restrict__ kg,
    const float* __restrict__ vg, const float* __restrict__ memk,
    const float* __restrict__ memv, const int* __restrict__ idxq,
    const int* __restrict__ idxk, float* __restrict__ outc)
{
  __shared__ float Ks[(MM + WW) * SK];   // 68 x 68 floats = 18.5 KB; becomes Ps
  __shared__ float Vs[(MM + WW) * SK];
  __shared__ int tq[WW];
  __shared__ int tk[WW];

  const int c = blockIdx.x, h = blockIdx.y, b = blockIdx.z;
  const int tid = threadIdx.x;
  const size_t bh = (size_t)(b * HH + h);

  if (tid < WW) tq[tid] = idxq[(bh * NCC + c) * WW + tid];
  else if (tid < 2 * WW) tk[tid - WW] = idxk[(bh * NCC + c) * WW + tid - WW];
  __syncthreads();

  const int r = tid >> 2, part = tid & 3;

  // Hoisted q-row load: issued before staging, consumed after the barrier.
  float qr[DD];
  {
    const float* qsrc = q + (bh * TT + tq[r]) * DD;
    #pragma unroll
    for (int i = 0; i < DD / 4; ++i) {
      float4 v = ((const float4*)qsrc)[i];
      qr[4*i] = v.x; qr[4*i+1] = v.y; qr[4*i+2] = v.z; qr[4*i+3] = v.w;
    }
  }

  for (int j = r; j < MM + WW; j += 64) {
    const float* sk = (j < MM)
        ? memk + (((size_t)(h * NCC + c)) * MM + j) * DD + part * 16
        : kg + (bh * TT + tk[j - MM]) * DD + part * 16;
    const float* sv = (j < MM)
        ? memv + (((size_t)(h * NCC + c)) * MM + j) * DD + part * 16
        : vg + (bh * TT + tk[j - MM]) * DD + part * 16;
    #pragma unroll
    for (int i = 0; i < 4; ++i) {
      *(float4*)&Ks[j * SK + part * 16 + 4 * i] = ((const float4*)sk)[i];
      *(float4*)&Vs[j * SK + part * 16 + 4 * i] = ((const float4*)sv)[i];
    }
  }
  __syncthreads();

  // QK^T: thread (r, part) handles keys j = part*17 + jj
  float s[17];
  {
    #pragma unroll
    for (int jj = 0; jj < 17; ++jj) {
      const float4* krow = (const float4*)&Ks[(part * 17 + jj) * SK];
      float a0 = 0.f, a1 = 0.f, a2 = 0.f, a3 = 0.f;
      #pragma unroll
      for (int i = 0; i < DD / 4; ++i) {
        float4 kv = krow[i];
        a0 = fmaf(qr[4*i+0], kv.x, a0);
        a1 = fmaf(qr[4*i+1], kv.y, a1);
        a2 = fmaf(qr[4*i+2], kv.z, a2);
        a3 = fmaf(qr[4*i+3], kv.w, a3);
      }
      s[jj] = ((a0 + a1) + (a2 + a3)) * 0.125f;
    }
  }
  // softmax across the quad (4 lanes = one query row)
  float mx = s[0];
  #pragma unroll
  for (int jj = 1; jj < 17; ++jj) mx = fmaxf(mx, s[jj]);
  mx = fmaxf(mx, __shfl_xor(mx, 1, 64));
  mx = fmaxf(mx, __shfl_xor(mx, 2, 64));
  float sum = 0.f;
  #pragma unroll
  for (int jj = 0; jj < 17; ++jj) { s[jj] = expf(s[jj] - mx); sum += s[jj]; }
  sum += __shfl_xor(sum, 1, 64);
  sum += __shfl_xor(sum, 2, 64);
  const float inv = 1.f / sum;
  #pragma unroll
  for (int jj = 0; jj < 17; ++jj) s[jj] *= inv;

  __syncthreads();                       // all QK reads of Ks complete
  #pragma unroll
  for (int jj = 0; jj < 17; ++jj) Ks[r * SK + part * 17 + jj] = s[jj];
  __syncthreads();                       // Ps ready

  // PV: thread (r, part) owns out[r][part*16 .. part*16+16) — constant-index accs
  float4 a0 = make_float4(0.f,0.f,0.f,0.f), a1 = a0, a2 = a0, a3 = a0;
  for (int j = 0; j < MM + WW; ++j) {
    const float p = Ks[r * SK + j];
    const float4* vrow = (const float4*)&Vs[j * SK + part * 16];
    float4 v0 = vrow[0], v1 = vrow[1], v2 = vrow[2], v3 = vrow[3];
    a0.x = fmaf(p, v0.x, a0.x); a0.y = fmaf(p, v0.y, a0.y);
    a0.z = fmaf(p, v0.z, a0.z); a0.w = fmaf(p, v0.w, a0.w);
    a1.x = fmaf(p, v1.x, a1.x); a1.y = fmaf(p, v1.y, a1.y);
    a1.z = fmaf(p, v1.z, a1.z); a1.w = fmaf(p, v1.w, a1.w);
    a2.x = fmaf(p, v2.x, a2.x); a2.y = fmaf(p, v2.y, a2.y);
    a2.z = fmaf(p, v2.z, a2.z); a2.w = fmaf(p, v2.w, a2.w);
    a3.x = fmaf(p, v3.x, a3.x); a3.y = fmaf(p, v3.y, a3.y);
    a3.z = fmaf(p, v3.z, a3.z); a3.w = fmaf(p, v3.w, a3.w);
  }
  float4* obase = (float4*)(outc + (((bh * NCC + c) * WW) + r) * DD + part * 16);
  obase[0] = a0; obase[1] = a1; obase[2] = a2; obase[3] = a3;
}

// ---------------- Kernel C2: inverted index (one int atomic per selection) ----------------
__global__ __launch_bounds__(256) void kindex(
    const int* __restrict__ idxq, const float* __restrict__ outc,
    int* __restrict__ cnt, int* __restrict__ slots, float* __restrict__ out)
{
  const int i = blockIdx.x * 256 + threadIdx.x;       // over B*H*NC*W
  const int bh = i >> 13;                             // NC*W = 8192
  const int e = i & 8191;
  const int t = idxq[i];
  const int row = bh * TT + t;
  const int p = atomicAdd(&cnt[row], 1);
  if (p < SMAX) {
    slots[(size_t)row * SMAX + p] = e;
  } else {
    const float* src = outc + ((size_t)(bh * (NCC * WW)) + e) * DD;
    for (int d = 0; d < DD; ++d) atomicAdd(&out[(size_t)row * DD + d], src[d]);
  }
}

// ---------------- Kernel D: gather slots + divide + aux ----------------
__global__ __launch_bounds__(256) void kfinal(
    float* __restrict__ outp, const int* __restrict__ cnt,
    const int* __restrict__ slots, const float* __restrict__ outc,
    const float* __restrict__ aux)
{
  const size_t n = (size_t)BB * HH * TT * DD;
  const size_t i = (size_t)blockIdx.x * 256 + threadIdx.x;
  if (i < n) {
    const int row = (int)(i >> 6);
    const int d = (int)(i & 63);
    const int bh = row >> 13;
    const int c = cnt[row];
    const int m = c < SMAX ? c : SMAX;
    float sum = outp[i];
    for (int s = 0; s < m; ++s) {
      const int e = slots[(size_t)row * SMAX + s];
      sum += outc[((size_t)(bh * (NCC * WW)) + e) * DD + d];
    }
    outp[i] = sum / ((float)c + 1e-5f);
  }
  if (i == 0) outp[n] = aux[0] * (0.0001f / (float)((size_t)BB * HH * 2 * TT * DD));
}

extern "C" void kernel_launch(void* const* d_in, const int* in_sizes, int n_in,
                              void* d_out, int out_size, void* d_ws, size_t ws_size,
                              hipStream_t stream) {
  (void)in_sizes; (void)n_in; (void)out_size; (void)ws_size;
  const float* q     = (const float*)d_in[0];
  const float* k     = (const float*)d_in[1];
  const float* v     = (const float*)d_in[2];
  const float* means = (const float*)d_in[3];
  const float* memk  = (const float*)d_in[4];
  const float* memv  = (const float*)d_in[5];
  float* out = (float*)d_out;

  const size_t NQ   = (size_t)BB * HH * NCC * TT;   // 16,777,216
  const size_t NIDX = (size_t)BB * HH * NCC * WW;   // 131,072
  const size_t NROW = (size_t)BB * HH * TT;         // 131,072
  const size_t NMIN = (size_t)BB * HH * T2;         // 262,144

  float*        qd   = (float*)d_ws;
  float*        kd   = qd + NQ;
  int*          idxq = (int*)(kd + NQ);
  int*          idxk = idxq + NIDX;
  int*          cnt  = idxk + NIDX;
  float*        aux  = (float*)(cnt + NROW);
  unsigned int* minb = (unsigned int*)(aux + 1);
  float*        outc  = qd;                         // dead after ktopk -> reuse
  int*          slots = (int*)kd;

  const size_t n = (size_t)BB * HH * TT * DD;
  hipMemsetAsync(out, 0, n * sizeof(float), stream);
  hipMemsetAsync(cnt, 0, (NROW + 1) * sizeof(int), stream);   // cnt + aux
  hipMemsetAsync(minb, 0x7f, NMIN * sizeof(unsigned int), stream);  // +inf-ish floats

  kdist<<<dim3(T2 / 256, HH, BB * 2), 256, 0, stream>>>(q, k, means, qd, kd, minb);
  kaux<<<(int)(NMIN / 256), 256, 0, stream>>>(minb, aux);
  ktopk<<<dim3(NCC, HH, 2 * BB), 256, 0, stream>>>(qd, kd, idxq, idxk);
  kattn<<<dim3(NCC, HH, BB), 256, 0, stream>>>(q, k, v, memk, memv, idxq, idxk, outc);
  kindex<<<(int)(NIDX / 256), 256, 0, stream>>>(idxq, outc, cnt, slots, out);
  kfinal<<<(int)((n + 255) / 256), 256, 0, stream>>>(out, cnt, slots, outc, aux);
}

// Round 11
// 406.988 us; speedup vs baseline: 1.0691x; 1.0251x over previous
//
#include <hip/hip_runtime.h>
#include <math.h>

#define BB 2
#define TT 8192
#define HH 8
#define DD 64
#define NCC 128
#define MM 4
#define WW (TT/NCC)     // 64
#define T2 (2*TT)
#define CH 64           // clusters per kdist block (c-split x2)
#define SMAX 128        // hard bound: a t appears <=1x per cluster's top-64 -> cnt<=NC=128.
                        // Overflow path DELETED (provably dead); slots fits in dead qd/kd.
#define SK 68           // LDS row stride: 68*4=272 B, 16B-aligned -> ds_read_b128
#define TIEMAX 256

// ---------------- Kernel A: normalize + cdist + per-t' min via atomicMin ----------------
// ROUND-3 VERBATIM — PERMANENTLY FROZEN. Means rows wave-uniform -> scalar
// s_load + v_fma(v,s,v); 116us, VALU 74%, occ 50%. Post-mortem rounds
// 1/4/7/8/9: VALU-busy TIME is ~86us in every variant; ILP/pin/launch_bounds
// only shifted occupancy and exposed MORE stall. The no-hint allocator's
// 40-VGPR choice maximizes resident waves = best stall hiding. Do not touch.
__global__ __launch_bounds__(256) void kdist(
    const float* __restrict__ q, const float* __restrict__ k,
    const float* __restrict__ means,
    float* __restrict__ qd, float* __restrict__ kd,
    unsigned int* __restrict__ minb)
{
  __shared__ float sm2[CH];
  const int b = blockIdx.z >> 1, h = blockIdx.y;
  const int c0 = (blockIdx.z & 1) * CH;
  const int tid = threadIdx.x;

  if (tid < CH) {
    const float* mrow = means + ((size_t)h * NCC + c0 + tid) * DD;
    float s = 0.f;
    #pragma unroll
    for (int d = 0; d < DD; ++d) { float v = mrow[d]; s += v * v; }
    sm2[tid] = s;
  }
  __syncthreads();

  const int tp = blockIdx.x * 256 + tid;               // t' in [0,2T)
  const size_t bh = (size_t)(b * HH + h);
  const float* src = (tp < TT) ? (q + (bh * TT + tp) * DD)
                               : (k + (bh * TT + (tp - TT)) * DD);
  float x[DD];
  float ss = 0.f;
  #pragma unroll
  for (int i = 0; i < DD / 4; ++i) {
    float4 v = ((const float4*)src)[i];
    x[4*i] = v.x; x[4*i+1] = v.y; x[4*i+2] = v.z; x[4*i+3] = v.w;
    ss += v.x*v.x + v.y*v.y + v.z*v.z + v.w*v.w;
  }
  const float scale = 1.f / (sqrtf(ss) + 1e-6f);
  float x2 = 0.f;
  #pragma unroll
  for (int i = 0; i < DD; ++i) { x[i] *= scale; x2 += x[i] * x[i]; }

  float* dst = (tp < TT) ? (qd + (bh * NCC) * TT + tp)
                         : (kd + (bh * NCC) * TT + (tp - TT));
  float mind2 = 1e30f;
  const float* mbase = means + ((size_t)h * NCC + c0) * DD;
  for (int c = 0; c < CH; ++c) {
    const float* mrow = mbase + (size_t)c * DD;        // wave-uniform -> s_load
    float dot = 0.f;
    #pragma unroll
    for (int d = 0; d < DD; ++d) dot += x[d] * mrow[d];
    float d2 = fmaxf(x2 + sm2[c] - 2.f * dot, 0.f);
    mind2 = fminf(mind2, d2);
    dst[(size_t)(c0 + c) * TT] = sqrtf(d2);
  }

  atomicMin(&minb[bh * T2 + tp], __float_as_uint(mind2));   // d2>=0: bits monotone
}

// ---------------- Kernel A2: sum per-t' minima -> aux ----------------
__global__ __launch_bounds__(256) void kaux(
    const unsigned int* __restrict__ minb, float* __restrict__ aux)
{
  __shared__ float red[4];
  const int i = blockIdx.x * 256 + threadIdx.x;        // over BB*HH*T2
  float v = __uint_as_float(minb[i]);
  #pragma unroll
  for (int off = 32; off; off >>= 1) v += __shfl_down(v, off, 64);
  if ((threadIdx.x & 63) == 0) red[threadIdx.x >> 6] = v;
  __syncthreads();
  if (threadIdx.x == 0) atomicAdd(aux, red[0] + red[1] + red[2] + red[3]);
}

// ---------------- Kernel B: top-64 smallest per row, register-resident ----------------
// Shuffle-reduce form (the 412.9us-measured config). Row in registers
// (u[32]/thread); bitwise binary search for tau; lowest-index ties match
// jax.lax.top_k.
__global__ __launch_bounds__(256) void ktopk(
    const float* __restrict__ qd, const float* __restrict__ kd,
    int* __restrict__ idxq, int* __restrict__ idxk)
{
  __shared__ unsigned int red[4];
  __shared__ int outIdx[WW];
  __shared__ int tie[TIEMAX];
  __shared__ int pos, tpos;

  const int c = blockIdx.x, h = blockIdx.y;
  const int b = blockIdx.z >> 1, isK = blockIdx.z & 1;
  const int tid = threadIdx.x;
  const int lane = tid & 63, wid = tid >> 6;
  const size_t rowoff = ((size_t)(b * HH + h) * NCC + c) * TT;
  const float4* row4 = (const float4*)((isK ? kd : qd) + rowoff);

  unsigned int u[32];
  #pragma unroll
  for (int j = 0; j < 8; ++j) {
    float4 v = row4[j * 256 + tid];          // u[4j+m] is at index j*1024+tid*4+m
    u[4*j+0] = __float_as_uint(v.x);
    u[4*j+1] = __float_as_uint(v.y);
    u[4*j+2] = __float_as_uint(v.z);
    u[4*j+3] = __float_as_uint(v.w);
  }
  if (tid == 0) { pos = 0; tpos = 0; }

  unsigned int tau = 0u;
  for (int bit = 30; bit >= 0; --bit) {      // bit31 = sign, always 0 for dist
    const unsigned int cand = tau | (1u << bit);
    int cnt = 0;
    #pragma unroll
    for (int i = 0; i < 32; ++i) cnt += (u[i] < cand) ? 1 : 0;
    #pragma unroll
    for (int off = 32; off; off >>= 1) cnt += __shfl_down(cnt, off, 64);
    if (lane == 0) red[wid] = (unsigned int)cnt;
    __syncthreads();
    const int tot = (int)(red[0] + red[1] + red[2] + red[3]);
    if (tot < WW) tau = cand;                // 64th smallest >= cand
    __syncthreads();
  }
  {
    int cnt = 0;
    #pragma unroll
    for (int i = 0; i < 32; ++i) cnt += (u[i] < tau) ? 1 : 0;
    #pragma unroll
    for (int off = 32; off; off >>= 1) cnt += __shfl_down(cnt, off, 64);
    if (lane == 0) red[wid] = (unsigned int)cnt;
  }
  __syncthreads();
  const int base = (int)(red[0] + red[1] + red[2] + red[3]);
  const int need = WW - base;

  #pragma unroll
  for (int i = 0; i < 32; ++i) {
    const int idx = (i >> 2) * 1024 + tid * 4 + (i & 3);
    if (u[i] < tau) {
      int p = atomicAdd(&pos, 1); outIdx[p] = idx;
    } else if (u[i] == tau) {
      int p = atomicAdd(&tpos, 1);
      if (p < TIEMAX) tie[p] = idx;          // >TIEMAX exact-equal values: pathological
    }
  }
  __syncthreads();
  const int tc = tpos < TIEMAX ? tpos : TIEMAX;
  if (tc == need) {
    if (tid < need) outIdx[base + tid] = tie[tid];   // all ties taken; order irrelevant
  } else if (tid == 0) {
    int last = -1;                            // rare: pick `need` lowest tie indices
    for (int e = 0; e < need; ++e) {
      int mn = 0x7fffffff;
      for (int s = 0; s < tc; ++s) { int t = tie[s]; if (t > last && t < mn) mn = t; }
      outIdx[base + e] = mn; last = mn;
    }
  }
  __syncthreads();
  int* dstp = (isK ? idxk : idxq) + ((size_t)(b * HH + h) * NCC + c) * WW;
  if (tid < WW) dstp[tid] = outIdx[tid];
}

// ---------------- Kernel C: gather + attention -> dense per-cluster out ----------------
// ROUND-3 VERBATIM (q-hoist reverted: measured neutral-to-negative, r10).
// grid: (NC, H, B), block 256. SK=68 -> b128 LDS reads. P round-trips through
// LDS; PV accumulators are CONSTANT-indexed float4. No atomics; coalesced stores.
__global__ __launch_bounds__(256) void kattn(
    const float* __restrict__ q, const float* __restrict__ kg,
    const float* __restrict__ vg, const float* __restrict__ memk,
    const float* __restrict__ memv, const int* __restrict__ idxq,
    const int* __restrict__ idxk, float* __restrict__ outc)
{
  __shared__ float Ks[(MM + WW) * SK];   // 68 x 68 floats = 18.5 KB; becomes Ps
  __shared__ float Vs[(MM + WW) * SK];
  __shared__ int tq[WW];
  __shared__ int tk[WW];

  const int c = blockIdx.x, h = blockIdx.y, b = blockIdx.z;
  const int tid = threadIdx.x;
  const size_t bh = (size_t)(b * HH + h);

  if (tid < WW) tq[tid] = idxq[(bh * NCC + c) * WW + tid];
  else if (tid < 2 * WW) tk[tid - WW] = idxk[(bh * NCC + c) * WW + tid - WW];
  __syncthreads();

  const int r = tid >> 2, part = tid & 3;

  for (int j = r; j < MM + WW; j += 64) {
    const float* sk = (j < MM)
        ? memk + (((size_t)(h * NCC + c)) * MM + j) * DD + part * 16
        : kg + (bh * TT + tk[j - MM]) * DD + part * 16;
    const float* sv = (j < MM)
        ? memv + (((size_t)(h * NCC + c)) * MM + j) * DD + part * 16
        : vg + (bh * TT + tk[j - MM]) * DD + part * 16;
    #pragma unroll
    for (int i = 0; i < 4; ++i) {
      *(float4*)&Ks[j * SK + part * 16 + 4 * i] = ((const float4*)sk)[i];
      *(float4*)&Vs[j * SK + part * 16 + 4 * i] = ((const float4*)sv)[i];
    }
  }
  __syncthreads();

  // QK^T: thread (r, part) handles keys j = part*17 + jj
  float s[17];
  {
    float qr[DD];
    const float* qsrc = q + (bh * TT + tq[r]) * DD;
    #pragma unroll
    for (int i = 0; i < DD / 4; ++i) {
      float4 v = ((const float4*)qsrc)[i];
      qr[4*i] = v.x; qr[4*i+1] = v.y; qr[4*i+2] = v.z; qr[4*i+3] = v.w;
    }
    #pragma unroll
    for (int jj = 0; jj < 17; ++jj) {
      const float4* krow = (const float4*)&Ks[(part * 17 + jj) * SK];
      float a0 = 0.f, a1 = 0.f, a2 = 0.f, a3 = 0.f;
      #pragma unroll
      for (int i = 0; i < DD / 4; ++i) {
        float4 kv = krow[i];
        a0 = fmaf(qr[4*i+0], kv.x, a0);
        a1 = fmaf(qr[4*i+1], kv.y, a1);
        a2 = fmaf(qr[4*i+2], kv.z, a2);
        a3 = fmaf(qr[4*i+3], kv.w, a3);
      }
      s[jj] = ((a0 + a1) + (a2 + a3)) * 0.125f;
    }
  }
  // softmax across the quad (4 lanes = one query row)
  float mx = s[0];
  #pragma unroll
  for (int jj = 1; jj < 17; ++jj) mx = fmaxf(mx, s[jj]);
  mx = fmaxf(mx, __shfl_xor(mx, 1, 64));
  mx = fmaxf(mx, __shfl_xor(mx, 2, 64));
  float sum = 0.f;
  #pragma unroll
  for (int jj = 0; jj < 17; ++jj) { s[jj] = expf(s[jj] - mx); sum += s[jj]; }
  sum += __shfl_xor(sum, 1, 64);
  sum += __shfl_xor(sum, 2, 64);
  const float inv = 1.f / sum;
  #pragma unroll
  for (int jj = 0; jj < 17; ++jj) s[jj] *= inv;

  __syncthreads();                       // all QK reads of Ks complete
  #pragma unroll
  for (int jj = 0; jj < 17; ++jj) Ks[r * SK + part * 17 + jj] = s[jj];
  __syncthreads();                       // Ps ready

  // PV: thread (r, part) owns out[r][part*16 .. part*16+16) — constant-index accs
  float4 a0 = make_float4(0.f,0.f,0.f,0.f), a1 = a0, a2 = a0, a3 = a0;
  for (int j = 0; j < MM + WW; ++j) {
    const float p = Ks[r * SK + j];
    const float4* vrow = (const float4*)&Vs[j * SK + part * 16];
    float4 v0 = vrow[0], v1 = vrow[1], v2 = vrow[2], v3 = vrow[3];
    a0.x = fmaf(p, v0.x, a0.x); a0.y = fmaf(p, v0.y, a0.y);
    a0.z = fmaf(p, v0.z, a0.z); a0.w = fmaf(p, v0.w, a0.w);
    a1.x = fmaf(p, v1.x, a1.x); a1.y = fmaf(p, v1.y, a1.y);
    a1.z = fmaf(p, v1.z, a1.z); a1.w = fmaf(p, v1.w, a1.w);
    a2.x = fmaf(p, v2.x, a2.x); a2.y = fmaf(p, v2.y, a2.y);
    a2.z = fmaf(p, v2.z, a2.z); a2.w = fmaf(p, v2.w, a2.w);
    a3.x = fmaf(p, v3.x, a3.x); a3.y = fmaf(p, v3.y, a3.y);
    a3.z = fmaf(p, v3.z, a3.z); a3.w = fmaf(p, v3.w, a3.w);
  }
  float4* obase = (float4*)(outc + (((bh * NCC + c) * WW) + r) * DD + part * 16);
  obase[0] = a0; obase[1] = a1; obase[2] = a2; obase[3] = a3;
}

// ---------------- Kernel C2: inverted index (one int atomic per selection) ----------------
// SMAX=128 >= hard cnt bound -> overflow path deleted; no outc dependency.
__global__ __launch_bounds__(256) void kindex(
    const int* __restrict__ idxq,
    int* __restrict__ cnt, int* __restrict__ slots)
{
  const int i = blockIdx.x * 256 + threadIdx.x;       // over B*H*NC*W
  const int bh = i >> 13;                             // NC*W = 8192
  const int e = i & 8191;
  const int t = idxq[i];
  const int row = bh * TT + t;
  const int p = atomicAdd(&cnt[row], 1);
  slots[(size_t)row * SMAX + p] = e;                  // p < 128 guaranteed
}

// ---------------- Kernel D: gather slots + divide + aux ----------------
// No overflow path -> no outp read, no prior memset of out; pure write.
__global__ __launch_bounds__(256) void kfinal(
    float* __restrict__ outp, const int* __restrict__ cnt,
    const int* __restrict__ slots, const float* __restrict__ outc,
    const float* __restrict__ aux)
{
  const size_t n = (size_t)BB * HH * TT * DD;
  const size_t i = (size_t)blockIdx.x * 256 + threadIdx.x;
  if (i < n) {
    const int row = (int)(i >> 6);
    const int d = (int)(i & 63);
    const int bh = row >> 13;
    const int c = cnt[row];
    float sum = 0.f;
    for (int s = 0; s < c; ++s) {
      const int e = slots[(size_t)row * SMAX + s];
      sum += outc[((size_t)(bh * (NCC * WW)) + e) * DD + d];
    }
    outp[i] = sum / ((float)c + 1e-5f);
  }
  if (i == 0) outp[n] = aux[0] * (0.0001f / (float)((size_t)BB * HH * 2 * TT * DD));
}

extern "C" void kernel_launch(void* const* d_in, const int* in_sizes, int n_in,
                              void* d_out, int out_size, void* d_ws, size_t ws_size,
                              hipStream_t stream) {
  (void)in_sizes; (void)n_in; (void)out_size; (void)ws_size;
  const float* q     = (const float*)d_in[0];
  const float* k     = (const float*)d_in[1];
  const float* v     = (const float*)d_in[2];
  const float* means = (const float*)d_in[3];
  const float* memk  = (const float*)d_in[4];
  const float* memv  = (const float*)d_in[5];
  float* out = (float*)d_out;

  const size_t NQ   = (size_t)BB * HH * NCC * TT;   // 16,777,216 floats (64 MB)
  const size_t NIDX = (size_t)BB * HH * NCC * WW;   // 131,072
  const size_t NROW = (size_t)BB * HH * TT;         // 131,072
  const size_t NMIN = (size_t)BB * HH * T2;         // 262,144
  const size_t NOUTC = NIDX * DD;                   // 8,388,608 floats (33.5 MB)

  // Layout: small live-long buffers first; qd/kd last so their 128 MB can be
  // reused (outc 33.5 MB + slots 67 MB = 100.6 MB) after ktopk. Same total
  // footprint as before (~130.6 MB).
  int*          idxq = (int*)d_ws;
  int*          idxk = idxq + NIDX;
  int*          cnt  = idxk + NIDX;
  float*        aux  = (float*)(cnt + NROW);
  unsigned int* minb = (unsigned int*)(aux + 1);
  float*        qd   = (float*)(minb + NMIN);
  float*        kd   = qd + NQ;
  float*        outc  = qd;                          // dead after ktopk -> reuse
  int*          slots = (int*)(qd + NOUTC);          // extends into kd region

  const size_t n = (size_t)BB * HH * TT * DD;
  hipMemsetAsync(cnt, 0, (NROW + 1) * sizeof(int), stream);        // cnt + aux
  hipMemsetAsync(minb, 0x7f, NMIN * sizeof(unsigned int), stream); // +inf-ish floats

  kdist<<<dim3(T2 / 256, HH, BB * 2), 256, 0, stream>>>(q, k, means, qd, kd, minb);
  kaux<<<(int)(NMIN / 256), 256, 0, stream>>>(minb, aux);
  ktopk<<<dim3(NCC, HH, 2 * BB), 256, 0, stream>>>(qd, kd, idxq, idxk);
  kattn<<<dim3(NCC, HH, BB), 256, 0, stream>>>(q, k, v, memk, memv, idxq, idxk, outc);
  kindex<<<(int)(NIDX / 256), 256, 0, stream>>>(idxq, cnt, slots);
  kfinal<<<(int)((n + 255) / 256), 256, 0, stream>>>(out, cnt, slots, outc, aux);
}